// Round 7
// baseline (978.295 us; speedup 1.0000x reference)
//
#include <hip/hip_runtime.h>
#include <hip/hip_bf16.h>
#include <cstdint>

// Sparse top-2 MoE (DBRX experts), MI355X gfx950.
// router -> scan -> assign
//   -> 4x { convert w1/v1 slice (2 experts) into LLC-resident reused buffer; proj chunk }
//   -> 2x { convert w2 slice (4 experts) into same buffer; down chunk }
//   -> combine.
// GEMM kernel identical to R6's proven one (846 TF effective, MfmaUtil 38.8%):
// 128x128 dual tiles, 4 waves, single-buffered LDS, 2 syncthreads/K-tile, all-bf16
// global_load_lds staging, XOR-swizzle (pre-swizzled source + swizzled read).
// The chunk pipeline removes ~0.8 GB of bf16 write-back + GEMM weight re-fetch:
// the 67 MB chunk buffer is rewritten in place each chunk and stays in the 256 MB L3.

#define T_TOK 4096
#define DHID  2048
#define NEXP  8
#define IDIM  4096
#define NSLOT (T_TOK * 2)

#define BM 128
#define BK 64

typedef __bf16 bf16x8 __attribute__((ext_vector_type(8)));
typedef __bf16 bf16x4 __attribute__((ext_vector_type(4)));
typedef float  f32x4  __attribute__((ext_vector_type(4)));

__device__ __forceinline__ void gload_lds16(const void* g, void* l) {
    __builtin_amdgcn_global_load_lds(
        (const __attribute__((address_space(1))) uint32_t*)g,
        (__attribute__((address_space(3))) uint32_t*)l, 16, 0, 0);
}

// ---------------- router ----------------
__global__ __launch_bounds__(256) void router_kernel(
    const float* __restrict__ x, const float* __restrict__ wr,
    __bf16* __restrict__ xb, int* __restrict__ topi, float* __restrict__ topg,
    int* __restrict__ cnt)
{
    int wave = threadIdx.x >> 6, lane = threadIdx.x & 63;
    int t = blockIdx.x * 4 + wave;
    const float4* xr = (const float4*)(x + (size_t)t * DHID);
    bf16x4* xbo = (bf16x4*)(xb + (size_t)t * DHID);
    float acc[NEXP];
#pragma unroll
    for (int e = 0; e < NEXP; ++e) acc[e] = 0.f;
#pragma unroll
    for (int j = 0; j < DHID / 256; ++j) {
        int d4 = lane + j * 64;
        float4 v = xr[d4];
        bf16x4 bv;
        bv[0] = (__bf16)v.x; bv[1] = (__bf16)v.y;
        bv[2] = (__bf16)v.z; bv[3] = (__bf16)v.w;
        xbo[d4] = bv;
#pragma unroll
        for (int e = 0; e < NEXP; ++e) {
            float4 w = ((const float4*)(wr + e * DHID))[d4];
            acc[e] += v.x * w.x + v.y * w.y + v.z * w.z + v.w * w.w;
        }
    }
#pragma unroll
    for (int e = 0; e < NEXP; ++e) {
#pragma unroll
        for (int s = 32; s > 0; s >>= 1) acc[e] += __shfl_xor(acc[e], s);
    }
    if (lane == 0) {
        int e0 = 0; float l0 = acc[0];
#pragma unroll
        for (int e = 1; e < NEXP; ++e) if (acc[e] > l0) { l0 = acc[e]; e0 = e; }
        int e1 = -1; float l1 = -3.4e38f;
#pragma unroll
        for (int e = 0; e < NEXP; ++e) if (e != e0 && acc[e] > l1) { l1 = acc[e]; e1 = e; }
        float g0 = 1.f / (1.f + __expf(l1 - l0));
        topi[t * 2] = e0; topi[t * 2 + 1] = e1;
        topg[t * 2] = g0; topg[t * 2 + 1] = 1.f - g0;
        atomicAdd(&cnt[e0], 1); atomicAdd(&cnt[e1], 1);
    }
}

__global__ void scan_kernel(const int* __restrict__ cnt, int* __restrict__ basep,
                            int* __restrict__ fill)
{
    if (threadIdx.x == 0 && blockIdx.x == 0) {
        int s = 0;
#pragma unroll
        for (int e = 0; e < NEXP; ++e) { basep[e] = s; s += cnt[e]; fill[e] = 0; }
    }
}

__global__ __launch_bounds__(256) void assign_kernel(
    const int* __restrict__ topi, const float* __restrict__ topg,
    const int* __restrict__ basep, int* __restrict__ fill,
    int* __restrict__ tok_of_slot, float* __restrict__ gate_of_slot,
    int* __restrict__ slot_of)
{
    int t = blockIdx.x * 256 + threadIdx.x;
    if (t >= T_TOK) return;
#pragma unroll
    for (int k = 0; k < 2; ++k) {
        int e = topi[t * 2 + k];
        int slot = basep[e] + atomicAdd(&fill[e], 1);
        tok_of_slot[slot] = t;
        gate_of_slot[slot] = topg[t * 2 + k];
        slot_of[t * 2 + k] = slot;
    }
}

// ---------------- fp32 -> bf16 chunk convert (1 or 2 tensors per launch) ----------------
__global__ __launch_bounds__(256) void convert2_kernel(
    const float* __restrict__ s1, __bf16* __restrict__ d1,
    const float* __restrict__ s2, __bf16* __restrict__ d2, size_t n8)
{
    for (size_t i = (size_t)blockIdx.x * 256 + threadIdx.x; i < n8;
         i += (size_t)gridDim.x * 256) {
        {
            const float4* s = (const float4*)(s1 + i * 8);
            float4 a = s[0], b = s[1];
            bf16x8 o;
            o[0]=(__bf16)a.x; o[1]=(__bf16)a.y; o[2]=(__bf16)a.z; o[3]=(__bf16)a.w;
            o[4]=(__bf16)b.x; o[5]=(__bf16)b.y; o[6]=(__bf16)b.z; o[7]=(__bf16)b.w;
            *(bf16x8*)(d1 + i * 8) = o;
        }
        if (s2) {
            const float4* s = (const float4*)(s2 + i * 8);
            float4 a = s[0], b = s[1];
            bf16x8 o;
            o[0]=(__bf16)a.x; o[1]=(__bf16)a.y; o[2]=(__bf16)a.z; o[3]=(__bf16)a.w;
            o[4]=(__bf16)b.x; o[5]=(__bf16)b.y; o[6]=(__bf16)b.z; o[7]=(__bf16)b.w;
            *(bf16x8*)(d2 + i * 8) = o;
        }
    }
}

// ---------------- dual GEMM (R6's proven kernel + chunk base e0) ----------------
// PASS 1 (proj): acc1 = X w1^T, acc2 = X v1^T over the SAME 128x128 (m,n) tile;
//                epilogue H = silu(acc1)*acc2. A=xb gather; n0 = bx*128.
// PASS 2 (down): dual-N: acc1 = H w2[n0..n0+128)^T, acc2 = H w2[n0+128..n0+256)^T;
//                epilogue outslot = gate*acc. A=H contig; n0 = bx*256.
// Wa/Wb are CHUNK-LOCAL bf16 weight bases; expert-in-chunk = blockIdx.z; global
// expert id = e0 + blockIdx.z (for cnt/basep/slots).
template <int PASS, int KDIM>
__global__ __launch_bounds__(256, 2) void moe_gemm(
    const __bf16* __restrict__ Abase,
    const __bf16* __restrict__ Wa, const __bf16* __restrict__ Wb,
    const int* __restrict__ tok_of_slot, const float* __restrict__ gate_of_slot,
    const int* __restrict__ cnt, const int* __restrict__ basep,
    __bf16* __restrict__ Out, int e0)
{
    int ez = blockIdx.z;          // chunk-local expert
    int eg = e0 + ez;             // global expert
    int ne = cnt[eg];
    int m0 = blockIdx.y * BM;
    if (m0 >= ne) return;
    int n0 = blockIdx.x * (PASS == 1 ? 128 : 256);
    int sbase = basep[eg] + m0;

    __shared__ __bf16 As[BM * BK];    // 16 KiB
    __shared__ __bf16 B1s[BM * BK];   // 16 KiB
    __shared__ __bf16 B2s[BM * BK];   // 16 KiB
    __shared__ int   toks[BM];
    __shared__ float gates[BM];

    int tid = threadIdx.x, lane = tid & 63, wave = tid >> 6;
    char* AsB = (char*)&As[0];
    char* B1B = (char*)&B1s[0];
    char* B2B = (char*)&B2s[0];

    if (PASS == 1) {
        if (tid < BM) toks[tid] = (m0 + tid < ne) ? tok_of_slot[sbase + tid] : 0;
    } else {
        if (tid < BM) gates[tid] = gate_of_slot[(m0 + tid < ne) ? (sbase + tid) : sbase];
    }
    __syncthreads();

    // A staging: 16 chunks of 1 KiB (wave-uniform dest), 4 gload_lds(16B)/thread.
    // Linear LDS dest + pre-swizzled global source column-chunk.
    const __bf16* a_src[4];
    int coff[4];
#pragma unroll
    for (int r = 0; r < 4; ++r) {
        int chunk = wave * 4 + r;
        int arow  = chunk * 8 + (lane >> 3);
        int csw   = (lane & 7) ^ (arow & 7);
        size_t rowbase;
        if (PASS == 1) {
            rowbase = (size_t)toks[arow] * KDIM;
        } else {
            int srow = (m0 + arow < ne) ? (sbase + arow) : sbase;
            rowbase = (size_t)srow * KDIM;
        }
        a_src[r] = Abase + rowbase + csw * 8;
        coff[r]  = chunk * 1024;
    }

    // B staging: chunk-local bf16 weights via gload_lds, same swizzle scheme.
    const __bf16* b1_src[4];
    const __bf16* b2_src[4];
    {
        const __bf16* Wae;
        const __bf16* Wbe;
        if (PASS == 1) {
            Wae = Wa + (size_t)ez * IDIM * DHID;
            Wbe = Wb + (size_t)ez * IDIM * DHID;
        } else {
            Wae = Wa + (size_t)ez * DHID * IDIM;
            Wbe = Wae + (size_t)128 * KDIM;
        }
#pragma unroll
        for (int r = 0; r < 4; ++r) {
            int chunk = wave * 4 + r;
            int brow  = chunk * 8 + (lane >> 3);
            int csw   = (lane & 7) ^ (brow & 7);
            b1_src[r] = Wae + (size_t)(n0 + brow) * KDIM + csw * 8;
            b2_src[r] = Wbe + (size_t)(n0 + brow) * KDIM + csw * 8;
        }
    }

    int wr0 = (wave >> 1) * 64, wc0 = (wave & 1) * 64;

    f32x4 acc1[4][4], acc2[4][4];
    f32x4 zf = {0.f, 0.f, 0.f, 0.f};
#pragma unroll
    for (int m = 0; m < 4; ++m)
#pragma unroll
        for (int n = 0; n < 4; ++n) { acc1[m][n] = zf; acc2[m][n] = zf; }

    const int NK = KDIM / BK;
    for (int t = 0; t < NK; ++t) {
        int ko = t * BK;
#pragma unroll
        for (int r = 0; r < 4; ++r) gload_lds16(a_src[r] + ko, AsB + coff[r]);
#pragma unroll
        for (int r = 0; r < 4; ++r) gload_lds16(b1_src[r] + ko, B1B + coff[r]);
#pragma unroll
        for (int r = 0; r < 4; ++r) gload_lds16(b2_src[r] + ko, B2B + coff[r]);
        __syncthreads();   // drains gload_lds (implicit vmcnt 0) + publishes LDS
#pragma unroll
        for (int ks = 0; ks < 2; ++ks) {
            int kb = ks * 64 + (lane >> 4) * 16;
            bf16x8 af[4], b1f[4], b2f[4];
#pragma unroll
            for (int m = 0; m < 4; ++m) {
                int row = wr0 + m * 16 + (lane & 15);
                af[m] = *(const bf16x8*)(AsB + row * 128 + (kb ^ ((row & 7) << 4)));
            }
#pragma unroll
            for (int n = 0; n < 4; ++n) {
                int row = wc0 + n * 16 + (lane & 15);
                int off = row * 128 + (kb ^ ((row & 7) << 4));
                b1f[n] = *(const bf16x8*)(B1B + off);
                b2f[n] = *(const bf16x8*)(B2B + off);
            }
#pragma unroll
            for (int m = 0; m < 4; ++m)
#pragma unroll
                for (int n = 0; n < 4; ++n) {
                    acc1[m][n] = __builtin_amdgcn_mfma_f32_16x16x32_bf16(af[m], b1f[n], acc1[m][n], 0, 0, 0);
                    acc2[m][n] = __builtin_amdgcn_mfma_f32_16x16x32_bf16(af[m], b2f[n], acc2[m][n], 0, 0, 0);
                }
        }
        __syncthreads();   // reads done before next tile's staging writes
    }

    // ---- epilogue
#pragma unroll
    for (int m = 0; m < 4; ++m) {
        int rbase = wr0 + m * 16 + ((lane >> 4) * 4);
#pragma unroll
        for (int n = 0; n < 4; ++n) {
            int col = wc0 + n * 16 + (lane & 15);
#pragma unroll
            for (int r = 0; r < 4; ++r) {
                int lrow = rbase + r;
                if (m0 + lrow < ne) {
                    if (PASS == 1) {
                        float a = acc1[m][n][r];
                        float b = acc2[m][n][r];
                        float h = (a / (1.f + __expf(-a))) * b;
                        Out[(size_t)(sbase + lrow) * IDIM + n0 + col] = (__bf16)h;
                    } else {
                        float g = gates[lrow];
                        size_t obase = (size_t)(sbase + lrow) * DHID + n0;
                        Out[obase + col]       = (__bf16)(acc1[m][n][r] * g);
                        Out[obase + 128 + col] = (__bf16)(acc2[m][n][r] * g);
                    }
                }
            }
        }
    }
}

// ---------------- combine ----------------
__global__ __launch_bounds__(256) void combine_kernel(
    const __bf16* __restrict__ outslot, const int* __restrict__ slot_of,
    float* __restrict__ out)
{
    int idx = blockIdx.x * 256 + threadIdx.x;
    int t = idx >> 8;
    int c = (idx & 255) * 8;
    int s0 = slot_of[t * 2], s1 = slot_of[t * 2 + 1];
    bf16x8 a = *(const bf16x8*)(outslot + (size_t)s0 * DHID + c);
    bf16x8 b = *(const bf16x8*)(outslot + (size_t)s1 * DHID + c);
    float4 o0, o1;
    o0.x = (float)a[0] + (float)b[0];
    o0.y = (float)a[1] + (float)b[1];
    o0.z = (float)a[2] + (float)b[2];
    o0.w = (float)a[3] + (float)b[3];
    o1.x = (float)a[4] + (float)b[4];
    o1.y = (float)a[5] + (float)b[5];
    o1.z = (float)a[6] + (float)b[6];
    o1.w = (float)a[7] + (float)b[7];
    *(float4*)(out + (size_t)t * DHID + c)     = o0;
    *(float4*)(out + (size_t)t * DHID + c + 4) = o1;
}

extern "C" void kernel_launch(void* const* d_in, const int* in_sizes, int n_in,
                              void* d_out, int out_size, void* d_ws, size_t ws_size,
                              hipStream_t stream)
{
    (void)in_sizes; (void)n_in; (void)out_size; (void)ws_size;
    const float* x  = (const float*)d_in[0];
    const float* wr = (const float*)d_in[1];
    const float* w1 = (const float*)d_in[2];
    const float* v1 = (const float*)d_in[3];
    const float* w2 = (const float*)d_in[4];
    float* out = (float*)d_out;

    char* ws = (char*)d_ws;
    size_t off = 0;
    auto alloc = [&](size_t bytes) -> void* {
        void* p = ws + off;
        off += bytes;
        off = (off + 255) & ~(size_t)255;
        return p;
    };
    __bf16* xb      = (__bf16*)alloc((size_t)T_TOK * DHID * 2);
    __bf16* H       = (__bf16*)alloc((size_t)NSLOT * IDIM * 2);
    __bf16* outslot = (__bf16*)alloc((size_t)NSLOT * DHID * 2);
    int*    topi    = (int*)  alloc((size_t)T_TOK * 2 * 4);
    float*  topg    = (float*)alloc((size_t)T_TOK * 2 * 4);
    int*    tok_of_slot  = (int*)  alloc((size_t)NSLOT * 4);
    float*  gate_of_slot = (float*)alloc((size_t)NSLOT * 4);
    int*    slot_of = (int*)  alloc((size_t)NSLOT * 4);
    int*    cnt     = (int*)  alloc(NEXP * 4);
    int*    basep   = (int*)  alloc(NEXP * 4);
    int*    fill    = (int*)  alloc(NEXP * 4);

    const size_t EW = (size_t)IDIM * DHID;        // 8.39M elems per expert per tensor
    // Reused chunk buffer: max(2 experts x {w1,v1}, 4 experts x w2) = 4*EW elems bf16 = 67 MB
    __bf16* chunkbuf = (__bf16*)alloc(4 * EW * 2);
    __bf16* pb1 = chunkbuf;            // 2-expert w1 slice
    __bf16* pb2 = chunkbuf + 2 * EW;   // 2-expert v1 slice
    __bf16* db  = chunkbuf;            // 4-expert w2 slice (same window, reused)

    hipMemsetAsync(cnt, 0, NEXP * 4, stream);
    router_kernel<<<T_TOK / 4, 256, 0, stream>>>(x, wr, xb, topi, topg, cnt);
    scan_kernel<<<1, 64, 0, stream>>>(cnt, basep, fill);
    assign_kernel<<<T_TOK / 256, 256, 0, stream>>>(topi, topg, basep, fill,
                                                   tok_of_slot, gate_of_slot, slot_of);

    // proj: 4 chunks of 2 experts. convert (LLC-resident reuse) then GEMM.
    for (int c = 0; c < 4; ++c) {
        int e0 = c * 2;
        convert2_kernel<<<2048, 256, 0, stream>>>(
            w1 + (size_t)e0 * EW, pb1, v1 + (size_t)e0 * EW, pb2, (2 * EW) / 8);
        moe_gemm<1, DHID><<<dim3(IDIM / 128, NSLOT / BM, 2), 256, 0, stream>>>(
            xb, pb1, pb2, tok_of_slot, gate_of_slot, cnt, basep, H, e0);
    }
    // down: 2 chunks of 4 experts.
    for (int c = 0; c < 2; ++c) {
        int e0 = c * 4;
        convert2_kernel<<<2048, 256, 0, stream>>>(
            w2 + (size_t)e0 * EW, db, nullptr, nullptr, (4 * EW) / 8);
        moe_gemm<2, IDIM><<<dim3(DHID / 256, NSLOT / BM, 4), 256, 0, stream>>>(
            H, db, nullptr, tok_of_slot, gate_of_slot, cnt, basep, outslot, e0);
    }
    combine_kernel<<<(T_TOK * DHID / 8) / 256, 256, 0, stream>>>(outslot, slot_of, out);
}

// Round 8
// 841.172 us; speedup vs baseline: 1.1630x; 1.1630x over previous
//
#include <hip/hip_runtime.h>
#include <hip/hip_bf16.h>
#include <cstdint>

// Sparse top-2 MoE (DBRX experts), MI355X gfx950.
// Launch graph:
//   memset(cnt) -> fused{router | convert w1,v1 -> bf16} -> scan -> assign
//     -> fused{proj GEMM (H = silu(X w1^T)*(X v1^T)) | convert w2 -> bf16}
//     -> down GEMM (outslot = gate*(H w2^T)) -> combine.
// GEMM kernel is R6's proven one (846 TF eff, MfmaUtil 38.8%, bank conflicts 0):
// 128x128 dual tiles, 4 waves, single-buffered LDS, 2 syncthreads/K-tile, all-bf16
// global_load_lds staging (linear LDS dest + pre-swizzled source, swizzled reads).
// Fusion mechanism: proj is compute-bound at 15.7% HBM -> the 0.4 GB w2 convert rides
// in spare BW via an extra blockIdx.z slice (grid-stride, exits before any barrier).

#define T_TOK 4096
#define DHID  2048
#define NEXP  8
#define IDIM  4096
#define NSLOT (T_TOK * 2)

#define BM 128
#define BK 64

typedef __bf16 bf16x8 __attribute__((ext_vector_type(8)));
typedef __bf16 bf16x4 __attribute__((ext_vector_type(4)));
typedef float  f32x4  __attribute__((ext_vector_type(4)));

__device__ __forceinline__ void gload_lds16(const void* g, void* l) {
    __builtin_amdgcn_global_load_lds(
        (const __attribute__((address_space(1))) uint32_t*)g,
        (__attribute__((address_space(3))) uint32_t*)l, 16, 0, 0);
}

__device__ __forceinline__ void cvt8(const float* __restrict__ s, __bf16* __restrict__ d,
                                     size_t i) {
    const float4* sp = (const float4*)(s + i * 8);
    float4 a = sp[0], b = sp[1];
    bf16x8 o;
    o[0]=(__bf16)a.x; o[1]=(__bf16)a.y; o[2]=(__bf16)a.z; o[3]=(__bf16)a.w;
    o[4]=(__bf16)b.x; o[5]=(__bf16)b.y; o[6]=(__bf16)b.z; o[7]=(__bf16)b.w;
    *(bf16x8*)(d + i * 8) = o;
}

// ---------------- fused router + w1/v1 convert ----------------
__global__ __launch_bounds__(256) void router_cvt_kernel(
    const float* __restrict__ x, const float* __restrict__ wr,
    __bf16* __restrict__ xb, int* __restrict__ topi, float* __restrict__ topg,
    int* __restrict__ cnt,
    const float* __restrict__ w1, __bf16* __restrict__ wb1,
    const float* __restrict__ v1, __bf16* __restrict__ wv1, size_t n8)
{
    if (blockIdx.x >= T_TOK / 4) {
        // convert role: stripe w1 and v1 (n8 vec8 elements each)
        size_t cb = blockIdx.x - T_TOK / 4;
        size_t gid = cb * 256 + threadIdx.x;
        size_t stride = (size_t)(gridDim.x - T_TOK / 4) * 256;
        for (size_t i = gid; i < n8; i += stride) {
            cvt8(w1, wb1, i);
            cvt8(v1, wv1, i);
        }
        return;
    }
    int wave = threadIdx.x >> 6, lane = threadIdx.x & 63;
    int t = blockIdx.x * 4 + wave;
    const float4* xr = (const float4*)(x + (size_t)t * DHID);
    bf16x4* xbo = (bf16x4*)(xb + (size_t)t * DHID);
    float acc[NEXP];
#pragma unroll
    for (int e = 0; e < NEXP; ++e) acc[e] = 0.f;
#pragma unroll
    for (int j = 0; j < DHID / 256; ++j) {
        int d4 = lane + j * 64;
        float4 v = xr[d4];
        bf16x4 bv;
        bv[0] = (__bf16)v.x; bv[1] = (__bf16)v.y;
        bv[2] = (__bf16)v.z; bv[3] = (__bf16)v.w;
        xbo[d4] = bv;
#pragma unroll
        for (int e = 0; e < NEXP; ++e) {
            float4 w = ((const float4*)(wr + e * DHID))[d4];
            acc[e] += v.x * w.x + v.y * w.y + v.z * w.z + v.w * w.w;
        }
    }
#pragma unroll
    for (int e = 0; e < NEXP; ++e) {
#pragma unroll
        for (int s = 32; s > 0; s >>= 1) acc[e] += __shfl_xor(acc[e], s);
    }
    if (lane == 0) {
        int e0 = 0; float l0 = acc[0];
#pragma unroll
        for (int e = 1; e < NEXP; ++e) if (acc[e] > l0) { l0 = acc[e]; e0 = e; }
        int e1 = -1; float l1 = -3.4e38f;
#pragma unroll
        for (int e = 0; e < NEXP; ++e) if (e != e0 && acc[e] > l1) { l1 = acc[e]; e1 = e; }
        float g0 = 1.f / (1.f + __expf(l1 - l0));
        topi[t * 2] = e0; topi[t * 2 + 1] = e1;
        topg[t * 2] = g0; topg[t * 2 + 1] = 1.f - g0;
        atomicAdd(&cnt[e0], 1); atomicAdd(&cnt[e1], 1);
    }
}

__global__ void scan_kernel(const int* __restrict__ cnt, int* __restrict__ basep,
                            int* __restrict__ fill)
{
    if (threadIdx.x == 0 && blockIdx.x == 0) {
        int s = 0;
#pragma unroll
        for (int e = 0; e < NEXP; ++e) { basep[e] = s; s += cnt[e]; fill[e] = 0; }
    }
}

__global__ __launch_bounds__(256) void assign_kernel(
    const int* __restrict__ topi, const float* __restrict__ topg,
    const int* __restrict__ basep, int* __restrict__ fill,
    int* __restrict__ tok_of_slot, float* __restrict__ gate_of_slot,
    int* __restrict__ slot_of)
{
    int t = blockIdx.x * 256 + threadIdx.x;
    if (t >= T_TOK) return;
#pragma unroll
    for (int k = 0; k < 2; ++k) {
        int e = topi[t * 2 + k];
        int slot = basep[e] + atomicAdd(&fill[e], 1);
        tok_of_slot[slot] = t;
        gate_of_slot[slot] = topg[t * 2 + k];
        slot_of[t * 2 + k] = slot;
    }
}

// ---------------- standalone convert (fallback path only) ----------------
__global__ __launch_bounds__(256) void convert_kernel(
    const float* __restrict__ src, __bf16* __restrict__ dst, size_t n8)
{
    for (size_t i = (size_t)blockIdx.x * 256 + threadIdx.x; i < n8;
         i += (size_t)gridDim.x * 256) cvt8(src, dst, i);
}

// ---------------- dual GEMM (R6's proven kernel + optional convert slice) ----------------
// PASS 1 (proj): acc1 = X w1^T, acc2 = X v1^T on the same 128x128 tile;
//                epilogue H = silu(acc1)*acc2. A=xb gather; n0 = bx*128.
//                blockIdx.z == NEXP (when launched with z=NEXP+1): grid-stride convert
//                of cvt_src -> cvt_dst (w2), exits before any barrier.
// PASS 2 (down): dual-N: acc = H w2[n0..n0+256)^T; epilogue outslot = gate*acc.
template <int PASS, int KDIM>
__global__ __launch_bounds__(256, 2) void moe_gemm(
    const __bf16* __restrict__ Abase,
    const __bf16* __restrict__ Wa, const __bf16* __restrict__ Wb,
    const int* __restrict__ tok_of_slot, const float* __restrict__ gate_of_slot,
    const int* __restrict__ cnt, const int* __restrict__ basep,
    __bf16* __restrict__ Out,
    const float* __restrict__ cvt_src, __bf16* __restrict__ cvt_dst, size_t cvt_n8)
{
    int e = blockIdx.z;
    if (e >= NEXP) {
        // fused convert role (proj launch only)
        size_t gid = ((size_t)blockIdx.y * gridDim.x + blockIdx.x) * 256 + threadIdx.x;
        size_t stride = (size_t)gridDim.x * gridDim.y * 256;
        for (size_t i = gid; i < cvt_n8; i += stride) cvt8(cvt_src, cvt_dst, i);
        return;
    }
    int ne = cnt[e];
    int m0 = blockIdx.y * BM;
    if (m0 >= ne) return;
    int n0 = blockIdx.x * (PASS == 1 ? 128 : 256);
    int sbase = basep[e] + m0;

    __shared__ __bf16 As[BM * BK];    // 16 KiB
    __shared__ __bf16 B1s[BM * BK];   // 16 KiB
    __shared__ __bf16 B2s[BM * BK];   // 16 KiB
    __shared__ int   toks[BM];
    __shared__ float gates[BM];

    int tid = threadIdx.x, lane = tid & 63, wave = tid >> 6;
    char* AsB = (char*)&As[0];
    char* B1B = (char*)&B1s[0];
    char* B2B = (char*)&B2s[0];

    if (PASS == 1) {
        if (tid < BM) toks[tid] = (m0 + tid < ne) ? tok_of_slot[sbase + tid] : 0;
    } else {
        if (tid < BM) gates[tid] = gate_of_slot[(m0 + tid < ne) ? (sbase + tid) : sbase];
    }
    __syncthreads();

    // A staging: 16 chunks of 1 KiB (wave-uniform dest), 4 gload_lds(16B)/thread.
    const __bf16* a_src[4];
    int coff[4];
#pragma unroll
    for (int r = 0; r < 4; ++r) {
        int chunk = wave * 4 + r;
        int arow  = chunk * 8 + (lane >> 3);
        int csw   = (lane & 7) ^ (arow & 7);
        size_t rowbase;
        if (PASS == 1) {
            rowbase = (size_t)toks[arow] * KDIM;
        } else {
            int srow = (m0 + arow < ne) ? (sbase + arow) : sbase;
            rowbase = (size_t)srow * KDIM;
        }
        a_src[r] = Abase + rowbase + csw * 8;
        coff[r]  = chunk * 1024;
    }

    // B staging: bf16 weights via gload_lds, same swizzle scheme.
    const __bf16* b1_src[4];
    const __bf16* b2_src[4];
    {
        const __bf16* Wae;
        const __bf16* Wbe;
        if (PASS == 1) {
            Wae = Wa + (size_t)e * IDIM * DHID;
            Wbe = Wb + (size_t)e * IDIM * DHID;
        } else {
            Wae = Wa + (size_t)e * DHID * IDIM;
            Wbe = Wae + (size_t)128 * KDIM;
        }
#pragma unroll
        for (int r = 0; r < 4; ++r) {
            int chunk = wave * 4 + r;
            int brow  = chunk * 8 + (lane >> 3);
            int csw   = (lane & 7) ^ (brow & 7);
            b1_src[r] = Wae + (size_t)(n0 + brow) * KDIM + csw * 8;
            b2_src[r] = Wbe + (size_t)(n0 + brow) * KDIM + csw * 8;
        }
    }

    int wr0 = (wave >> 1) * 64, wc0 = (wave & 1) * 64;

    f32x4 acc1[4][4], acc2[4][4];
    f32x4 zf = {0.f, 0.f, 0.f, 0.f};
#pragma unroll
    for (int m = 0; m < 4; ++m)
#pragma unroll
        for (int n = 0; n < 4; ++n) { acc1[m][n] = zf; acc2[m][n] = zf; }

    const int NK = KDIM / BK;
    for (int t = 0; t < NK; ++t) {
        int ko = t * BK;
#pragma unroll
        for (int r = 0; r < 4; ++r) gload_lds16(a_src[r] + ko, AsB + coff[r]);
#pragma unroll
        for (int r = 0; r < 4; ++r) gload_lds16(b1_src[r] + ko, B1B + coff[r]);
#pragma unroll
        for (int r = 0; r < 4; ++r) gload_lds16(b2_src[r] + ko, B2B + coff[r]);
        __syncthreads();   // drains gload_lds (implicit vmcnt 0) + publishes LDS
#pragma unroll
        for (int ks = 0; ks < 2; ++ks) {
            int kb = ks * 64 + (lane >> 4) * 16;
            bf16x8 af[4], b1f[4], b2f[4];
#pragma unroll
            for (int m = 0; m < 4; ++m) {
                int row = wr0 + m * 16 + (lane & 15);
                af[m] = *(const bf16x8*)(AsB + row * 128 + (kb ^ ((row & 7) << 4)));
            }
#pragma unroll
            for (int n = 0; n < 4; ++n) {
                int row = wc0 + n * 16 + (lane & 15);
                int off = row * 128 + (kb ^ ((row & 7) << 4));
                b1f[n] = *(const bf16x8*)(B1B + off);
                b2f[n] = *(const bf16x8*)(B2B + off);
            }
#pragma unroll
            for (int m = 0; m < 4; ++m)
#pragma unroll
                for (int n = 0; n < 4; ++n) {
                    acc1[m][n] = __builtin_amdgcn_mfma_f32_16x16x32_bf16(af[m], b1f[n], acc1[m][n], 0, 0, 0);
                    acc2[m][n] = __builtin_amdgcn_mfma_f32_16x16x32_bf16(af[m], b2f[n], acc2[m][n], 0, 0, 0);
                }
        }
        __syncthreads();   // reads done before next tile's staging writes
    }

    // ---- epilogue
#pragma unroll
    for (int m = 0; m < 4; ++m) {
        int rbase = wr0 + m * 16 + ((lane >> 4) * 4);
#pragma unroll
        for (int n = 0; n < 4; ++n) {
            int col = wc0 + n * 16 + (lane & 15);
#pragma unroll
            for (int r = 0; r < 4; ++r) {
                int lrow = rbase + r;
                if (m0 + lrow < ne) {
                    if (PASS == 1) {
                        float a = acc1[m][n][r];
                        float b = acc2[m][n][r];
                        float h = (a / (1.f + __expf(-a))) * b;
                        Out[(size_t)(sbase + lrow) * IDIM + n0 + col] = (__bf16)h;
                    } else {
                        float g = gates[lrow];
                        size_t obase = (size_t)(sbase + lrow) * DHID + n0;
                        Out[obase + col]       = (__bf16)(acc1[m][n][r] * g);
                        Out[obase + 128 + col] = (__bf16)(acc2[m][n][r] * g);
                    }
                }
            }
        }
    }
}

// ---------------- combine ----------------
__global__ __launch_bounds__(256) void combine_kernel(
    const __bf16* __restrict__ outslot, const int* __restrict__ slot_of,
    float* __restrict__ out)
{
    int idx = blockIdx.x * 256 + threadIdx.x;
    int t = idx >> 8;
    int c = (idx & 255) * 8;
    int s0 = slot_of[t * 2], s1 = slot_of[t * 2 + 1];
    bf16x8 a = *(const bf16x8*)(outslot + (size_t)s0 * DHID + c);
    bf16x8 b = *(const bf16x8*)(outslot + (size_t)s1 * DHID + c);
    float4 o0, o1;
    o0.x = (float)a[0] + (float)b[0];
    o0.y = (float)a[1] + (float)b[1];
    o0.z = (float)a[2] + (float)b[2];
    o0.w = (float)a[3] + (float)b[3];
    o1.x = (float)a[4] + (float)b[4];
    o1.y = (float)a[5] + (float)b[5];
    o1.z = (float)a[6] + (float)b[6];
    o1.w = (float)a[7] + (float)b[7];
    *(float4*)(out + (size_t)t * DHID + c)     = o0;
    *(float4*)(out + (size_t)t * DHID + c + 4) = o1;
}

extern "C" void kernel_launch(void* const* d_in, const int* in_sizes, int n_in,
                              void* d_out, int out_size, void* d_ws, size_t ws_size,
                              hipStream_t stream)
{
    (void)in_sizes; (void)n_in; (void)out_size;
    const float* x  = (const float*)d_in[0];
    const float* wr = (const float*)d_in[1];
    const float* w1 = (const float*)d_in[2];
    const float* v1 = (const float*)d_in[3];
    const float* w2 = (const float*)d_in[4];
    float* out = (float*)d_out;

    char* ws = (char*)d_ws;
    size_t off = 0;
    auto alloc = [&](size_t bytes) -> void* {
        void* p = ws + off;
        off += bytes;
        off = (off + 255) & ~(size_t)255;
        return p;
    };
    __bf16* xb      = (__bf16*)alloc((size_t)T_TOK * DHID * 2);
    __bf16* H       = (__bf16*)alloc((size_t)NSLOT * IDIM * 2);
    __bf16* outslot = (__bf16*)alloc((size_t)NSLOT * DHID * 2);
    int*    topi    = (int*)  alloc((size_t)T_TOK * 2 * 4);
    float*  topg    = (float*)alloc((size_t)T_TOK * 2 * 4);
    int*    tok_of_slot  = (int*)  alloc((size_t)NSLOT * 4);
    float*  gate_of_slot = (float*)alloc((size_t)NSLOT * 4);
    int*    slot_of = (int*)  alloc((size_t)NSLOT * 4);
    int*    cnt     = (int*)  alloc(NEXP * 4);
    int*    basep   = (int*)  alloc(NEXP * 4);
    int*    fill    = (int*)  alloc(NEXP * 4);

    const size_t EW   = (size_t)IDIM * DHID;       // 8.39M elems / expert / tensor
    const size_t WALL = (size_t)NEXP * EW;         // 67.1M elems / tensor
    __bf16* wb1 = (__bf16*)alloc(WALL * 2);
    __bf16* wv1 = (__bf16*)alloc(WALL * 2);
    bool roomy = (ws_size >= off + WALL * 2 + (16u << 20));
    __bf16* wb2 = roomy ? (__bf16*)alloc(WALL * 2) : wb1;   // fallback: alias (serial path)

    hipMemsetAsync(cnt, 0, NEXP * 4, stream);
    // fused: router (blocks 0..1023) + w1/v1 convert (blocks 1024..5119)
    router_cvt_kernel<<<T_TOK / 4 + 4096, 256, 0, stream>>>(
        x, wr, xb, topi, topg, cnt, w1, wb1, v1, wv1, WALL / 8);
    scan_kernel<<<1, 64, 0, stream>>>(cnt, basep, fill);
    assign_kernel<<<T_TOK / 256, 256, 0, stream>>>(topi, topg, basep, fill,
                                                   tok_of_slot, gate_of_slot, slot_of);
    if (roomy) {
        // proj with fused w2 convert in the z==NEXP slice
        moe_gemm<1, DHID><<<dim3(IDIM / 128, NSLOT / BM, NEXP + 1), 256, 0, stream>>>(
            xb, wb1, wv1, tok_of_slot, gate_of_slot, cnt, basep, H, w2, wb2, WALL / 8);
    } else {
        moe_gemm<1, DHID><<<dim3(IDIM / 128, NSLOT / BM, NEXP), 256, 0, stream>>>(
            xb, wb1, wv1, tok_of_slot, gate_of_slot, cnt, basep, H, nullptr, nullptr, 0);
        convert_kernel<<<2048, 256, 0, stream>>>(w2, wb2, WALL / 8);
    }
    moe_gemm<2, IDIM><<<dim3(DHID / 256, NSLOT / BM, NEXP), 256, 0, stream>>>(
        H, wb2, nullptr, tok_of_slot, gate_of_slot, cnt, basep, outslot,
        nullptr, nullptr, 0);
    combine_kernel<<<(T_TOK * DHID / 8) / 256, 256, 0, stream>>>(outslot, slot_of, out);
}